// Round 12
// baseline (829.168 us; speedup 1.0000x reference)
//
#include <hip/hip_runtime.h>
#include <hip/hip_fp16.h>

// SpatialAttention fp32: B=128, C=3, H=W=256, 8x8 patches, FEAT=192, ENC=16.
// R16: per-wave software pipeline -- the MLP/latency ablation.
// Evidence: R15 (one barrier, DPP reduce, free-run) still stalls ~43us with
// issue ~18us; no throughput counter near ceiling. Little's law: 2.5TB/s x
// ~600ns needs ~6KB/CU in flight; each wave loads 6KB ONCE at birth then
// never again -> ~1-2 loading waves/CU = bare minimum; every wave eats full
// x latency. Fix: each wave owns 4 tiles x 8 patches (one jj-row, 32
// patches; grid 1024). Loop: cvt+encode(t) -> issue halfA loads(t+1) ->
// decode(t) -> issue halfB(t+1) -> store(t). Next tile's 6KB is in flight
// under ~2k cy of compute -> loads always outstanding. Also amortizes
// weight staging 4x. Reg plan: peak o24+hu8+raw12+addr ~56 <= 64 -> stays
// 8 waves/SIMD (VGPR_Count is physical; R12's spill matched demand-32).
// Tripwires: VGPR 48-64 & WRITE ~98.3MB (spill); absmax ~1.22e-4;
// dur 52-58 + VALU ~33% => DS-pipe residual -> strip decoder LDS next.

constexpr float L2E = 1.4426950408889634f;

typedef __fp16 h2 __attribute__((ext_vector_type(2)));

__device__ __forceinline__ float dot2(unsigned int w, h2 xp, float c) {
#if __has_builtin(__builtin_amdgcn_fdot2)
  return __builtin_amdgcn_fdot2(__builtin_bit_cast(h2, w), xp, c, false);
#else
  const h2 wh = __builtin_bit_cast(h2, w);
  return fmaf((float)wh.x, (float)xp.x, fmaf((float)wh.y, (float)xp.y, c));
#endif
}

// Sum across each aligned 8-lane octet (s = 0..7 within octet). Pure VALU.
__device__ __forceinline__ float oct_sum(float v) {
  v += __int_as_float(__builtin_amdgcn_update_dpp(
         0, __float_as_int(v), 0x0B1, 0xf, 0xf, true));  // quad_perm [1,0,3,2]
  v += __int_as_float(__builtin_amdgcn_update_dpp(
         0, __float_as_int(v), 0x04E, 0xf, 0xf, true));  // quad_perm [2,3,0,1]
  v += __int_as_float(__builtin_amdgcn_update_dpp(
         0, __float_as_int(v), 0x141, 0xf, 0xf, true));  // row_half_mirror
  return v;
}

// ---- one-time: Wenc (3072 f32) + Wdec (3072 f32) -> f16 in workspace ----
__global__ void prep_weights(const float* __restrict__ Wenc,
                             const float* __restrict__ Wdec,
                             __half* __restrict__ wenc_h,   // ws + 0
                             __half* __restrict__ wdec_h) { // ws + 3072
  const int t = blockIdx.x * 512 + threadIdx.x;
  if (t < 3072) {
    wenc_h[t] = __float2half_rn(Wenc[t]);
    wdec_h[t] = __float2half_rn(Wdec[t]);
  }
}

__global__ __launch_bounds__(256, 8) void spatial_attn(
    const float* __restrict__ x,             // [128][3][256][256]
    const unsigned int* __restrict__ wenc_u, // f16-pairs [16][96]
    const unsigned int* __restrict__ wdec_u, // f16-pairs [192][8] (f-major)
    const float* __restrict__ benc,          // [16]
    const float* __restrict__ bdec,          // [192]
    float* __restrict__ y)                   // [128][3][256][256]
{
  __shared__ __align__(16) unsigned int wencl[1536];  // [e][96 pairs]
  __shared__ __align__(16) unsigned int wdecl[1568];  // [s][196]: 192 + 4 pad
  __shared__ __align__(16) float        bdecl[224];   // [s][28]: 24 + 4 pad

  const int tid  = threadIdx.x;
  const int lane = tid & 63;
  const int wv   = tid >> 6;        // wave 0..3
  const int g    = lane >> 3;       // patch within tile
  const int s    = lane & 7;        // feature octant

  // ---- Stage weights into LDS (coalesced; wdec gets +4-uint/s pad) ----
  #pragma unroll
  for (int k = 0; k < 6; ++k) {
    const int i = k * 256 + tid;
    wencl[i] = wenc_u[i];
    wdecl[i + (i / 192) * 4] = wdec_u[i];
  }
  if (tid < 192) bdecl[(tid / 24) * 28 + (tid % 24)] = bdec[tid];

  // ---- Wave owns one full jj-row: 32 patches = 4 tiles of 8 ----
  const int pw = blockIdx.x * 128 + wv * 32;     // multiple of 32
  const int b  = pw >> 10;
  const int ii = (pw >> 5) & 31;
  // per-lane byte-element offsets for rows cr=3s..3s+2 of patch g, tile 0
  unsigned roff[3];
  #pragma unroll
  for (int tt = 0; tt < 3; ++tt) {
    const int cr = 3 * s + tt;
    roff[tt] = (unsigned)(b * 196608 + ii * 2048 + g * 8 +
                          (cr >> 3) * 65536 + (cr & 7) * 256);
  }
  __syncthreads();                  // the ONLY barrier: weights staged

  // ---- Prologue: tile 0 raw loads (6 x float4 in flight) ----
  float4 ra[3], rb[3];
  #pragma unroll
  for (int tt = 0; tt < 3; ++tt) {
    ra[tt] = *(const float4*)(x + roff[tt]);
    rb[tt] = *(const float4*)(x + roff[tt] + 4);
  }

  for (int t = 0; t < 4; ++t) {
    // ---- convert raw -> 12 half2 (frees ra/rb for prefetch) ----
    h2 xh[12];
    #pragma unroll
    for (int tt = 0; tt < 3; ++tt) {
      xh[tt*4+0] = __builtin_amdgcn_cvt_pkrtz(ra[tt].x, ra[tt].y);
      xh[tt*4+1] = __builtin_amdgcn_cvt_pkrtz(ra[tt].z, ra[tt].w);
      xh[tt*4+2] = __builtin_amdgcn_cvt_pkrtz(rb[tt].x, rb[tt].y);
      xh[tt*4+3] = __builtin_amdgcn_cvt_pkrtz(rb[tt].z, rb[tt].w);
    }

    // ---- Encoder: 12 dot2 per e; octet DPP reduce; bias+relu ----
    float h[16];
    const int we_off = s * 12;
    #pragma unroll
    for (int e = 0; e < 16; ++e) {
      const uint4 w0 = *(const uint4*)(wencl + e * 96 + we_off);
      const uint4 w1 = *(const uint4*)(wencl + e * 96 + we_off + 4);
      const uint4 w2 = *(const uint4*)(wencl + e * 96 + we_off + 8);
      float a = 0.0f;
      a = dot2(w0.x, xh[0], a);  a = dot2(w0.y, xh[1], a);
      a = dot2(w0.z, xh[2], a);  a = dot2(w0.w, xh[3], a);
      a = dot2(w1.x, xh[4], a);  a = dot2(w1.y, xh[5], a);
      a = dot2(w1.z, xh[6], a);  a = dot2(w1.w, xh[7], a);
      a = dot2(w2.x, xh[8], a);  a = dot2(w2.y, xh[9], a);
      a = dot2(w2.z, xh[10], a); a = dot2(w2.w, xh[11], a);
      a = oct_sum(a);                     // full 192-feature dot, replicated
      h[e] = fmaxf(a + benc[e], 0.0f);    // benc: wave-uniform s_load
    }
    h2 hu[8];
    #pragma unroll
    for (int k = 0; k < 8; ++k)
      hu[k] = __builtin_amdgcn_cvt_pkrtz(h[2*k], h[2*k+1]);

    // ---- Prefetch half A of tile t+1 (overlaps decoder) ----
    if (t < 3) {
      #pragma unroll
      for (int tt = 0; tt < 3; ++tt)
        ra[tt] = *(const float4*)(x + roff[tt] + (t + 1) * 64);
    }

    // ---- Decoder: my 24 outputs (f = s*24+q) ----
    float o[24];
    #pragma unroll
    for (int m = 0; m < 6; ++m) {
      const float4 bv = *(const float4*)(bdecl + s * 28 + 4 * m);
      o[4*m+0] = bv.x; o[4*m+1] = bv.y; o[4*m+2] = bv.z; o[4*m+3] = bv.w;
    }
    float ss = 0.0f;
    const int wd_off = s * 196;
    #pragma unroll
    for (int q = 0; q < 24; ++q) {
      const uint4 wa = *(const uint4*)(wdecl + wd_off + q * 8);
      const uint4 wb = *(const uint4*)(wdecl + wd_off + q * 8 + 4);
      float v = o[q];
      v = dot2(wa.x, hu[0], v); v = dot2(wa.y, hu[1], v);
      v = dot2(wa.z, hu[2], v); v = dot2(wa.w, hu[3], v);
      v = dot2(wb.x, hu[4], v); v = dot2(wb.y, hu[5], v);
      v = dot2(wb.z, hu[6], v); v = dot2(wb.w, hu[7], v);
      v = fmaxf(v, 0.0f);
      o[q] = v;
      ss += __builtin_amdgcn_exp2f(v * L2E);   // out>=0: no max-sub needed
    }

    // ---- Prefetch half B of tile t+1 (overlaps softmax+epilogue) ----
    if (t < 3) {
      #pragma unroll
      for (int tt = 0; tt < 3; ++tt)
        rb[tt] = *(const float4*)(x + roff[tt] + (t + 1) * 64 + 4);
    }

    // ---- Softmax denom (octet DPP) + y = softmax(out)*out stores ----
    ss = oct_sum(ss);
    const float inv = __builtin_amdgcn_rcpf(ss);
    #pragma unroll
    for (int tt = 0; tt < 3; ++tt) {
      float* dst = y + roff[tt] + t * 64;
      float r[8];
      #pragma unroll
      for (int c = 0; c < 8; ++c) {
        const float ov = o[tt * 8 + c];
        r[c] = __builtin_amdgcn_exp2f(ov * L2E) * inv * ov;
      }
      *(float4*)(dst)     = (float4){r[0], r[1], r[2], r[3]};
      *(float4*)(dst + 4) = (float4){r[4], r[5], r[6], r[7]};
    }
  }
}

extern "C" void kernel_launch(void* const* d_in, const int* in_sizes, int n_in,
                              void* d_out, int out_size, void* d_ws, size_t ws_size,
                              hipStream_t stream) {
  const float* x    = (const float*)d_in[0];
  const float* Wenc = (const float*)d_in[1];
  const float* benc = (const float*)d_in[2];
  const float* Wdec = (const float*)d_in[3];
  const float* bdec = (const float*)d_in[4];
  float* y = (float*)d_out;

  __half* wenc_h = (__half*)d_ws;           // 3072 f16 = 6 KB
  __half* wdec_h = wenc_h + 3072;           // 3072 f16 = 6 KB

  hipLaunchKernelGGL(prep_weights, dim3(6), dim3(512), 0, stream,
                     Wenc, Wdec, wenc_h, wdec_h);
  hipLaunchKernelGGL(spatial_attn, dim3(1024), dim3(256), 0, stream,
                     x, (const unsigned int*)wenc_h,
                     (const unsigned int*)wdec_h, benc, bdec, y);
}